// Round 2
// baseline (1258.928 us; speedup 1.0000x reference)
//
#include <hip/hip_runtime.h>
#include <hip/hip_bf16.h>

#define MAXD 32

struct EdgeParams {
  const int* e[6];
  int E[6];
  int ebase[6];
  int nbase[6];
};

// Build ELL adjacency for all 6 levels in one kernel. cnt must be zeroed.
__global__ void k_fill(EdgeParams p, int* __restrict__ cnt, int* __restrict__ ell, int ET) {
  for (int idx = blockIdx.x * blockDim.x + threadIdx.x; idx < ET; idx += gridDim.x * blockDim.x) {
    int l;
    if (idx < p.ebase[1]) l = 0;
    else if (idx < p.ebase[2]) l = 1;
    else if (idx < p.ebase[3]) l = 2;
    else if (idx < p.ebase[4]) l = 3;
    else if (idx < p.ebase[5]) l = 4;
    else l = 5;
    int e = idx - p.ebase[l];
    const int* epp = p.e[l];
    int row = epp[e];
    int col = epp[p.E[l] + e];
    int g = p.nbase[l] + row;
    int slot = atomicAdd(&cnt[g], 1);
    if (slot < MAXD) ell[g * MAXD + slot] = col;
  }
}

__global__ void k_dinv(const int* __restrict__ cnt, float* __restrict__ dinv, int NT) {
  int i = blockIdx.x * blockDim.x + threadIdx.x;
  if (i < NT) {
    int d = cnt[i];
    dinv[i] = d > 0 ? rsqrtf((float)d) : 0.0f;
  }
}

// t1[i,c] = -dinv[i] * sum_j dinv[col_j] * X[col_j, c]
__global__ void k_prop(const float* __restrict__ X, float* __restrict__ T,
                       const int* __restrict__ cnt, const int* __restrict__ ell,
                       const float* __restrict__ dinv, int nbase, int n, int C) {
  int total = n * C;
  for (int idx = blockIdx.x * blockDim.x + threadIdx.x; idx < total; idx += gridDim.x * blockDim.x) {
    unsigned ui = (unsigned)idx / (unsigned)C;
    int i = (int)ui;
    int c = idx - i * C;
    int g = nbase + i;
    int d = cnt[g]; if (d > MAXD) d = MAXD;
    const int* cols = ell + (long)g * MAXD;
    float acc = 0.f;
    for (int t = 0; t < d; ++t) {
      int cj = cols[t];
      acc += dinv[nbase + cj] * X[(long)cj * C + c];
    }
    T[idx] = -dinv[g] * acc;
  }
}

// Fused: compute t2 chunk in LDS (gather over t1), then [X|t1|t2] @ W + b (+relu).
// Block: 64 threads = 64 output columns; ROWS rows per block.
template <int ROWS>
__global__ void k_combine(const float* __restrict__ X, const float* __restrict__ T1,
                          const float* __restrict__ W, const float* __restrict__ B,
                          const int* __restrict__ cnt, const int* __restrict__ ell,
                          const float* __restrict__ dinv,
                          int nbase, int n, int Cin, int Cout, int doRelu,
                          float* __restrict__ OUT) {
  int colTiles = (Cout + 63) >> 6;
  int ct = blockIdx.x % colTiles;
  int rt = blockIdx.x / colTiles;
  int r0 = rt * ROWS;
  int tid = threadIdx.x;
  int o = ct * 64 + tid;
  int oc = (o < Cout) ? o : (Cout - 1);  // clamp for safe loads

  __shared__ float sx[ROWS][64];
  __shared__ float st1[ROWS][64];
  __shared__ float st2[ROWS][64];

  float acc[ROWS];
#pragma unroll
  for (int r = 0; r < ROWS; ++r) acc[r] = 0.f;

  for (int k0 = 0; k0 < Cin; k0 += 64) {
    int kw = Cin - k0; if (kw > 64) kw = 64;
    // stage X, t1 chunks
    for (int r = 0; r < ROWS; ++r) {
      int i = r0 + r;
      float vx = 0.f, vt = 0.f;
      if (i < n && tid < kw) {
        vx = X[(long)i * Cin + k0 + tid];
        vt = T1[(long)i * Cin + k0 + tid];
      }
      sx[r][tid] = vx;
      st1[r][tid] = vt;
    }
    __syncthreads();
    // t2 chunk: t2 = -2*dinv[i]*sum_j dinv[j]*t1[j] - x
    for (int r = 0; r < ROWS; ++r) {
      int i = r0 + r;
      float v = 0.f;
      if (i < n && tid < kw) {
        int g = nbase + i;
        int d = cnt[g]; if (d > MAXD) d = MAXD;
        const int* cols = ell + (long)g * MAXD;
        float a2 = 0.f;
        for (int t = 0; t < d; ++t) {
          int cj = cols[t];
          a2 += dinv[nbase + cj] * T1[(long)cj * Cin + k0 + tid];
        }
        v = -2.f * dinv[g] * a2 - sx[r][tid];
      }
      st2[r][tid] = v;
    }
    __syncthreads();
    // matmul chunk
    const float* W0 = W + ((long)(0 * Cin + k0)) * Cout + oc;
    const float* W1 = W + ((long)(1 * Cin + k0)) * Cout + oc;
    const float* W2 = W + ((long)(2 * Cin + k0)) * Cout + oc;
    for (int kk = 0; kk < kw; ++kk) {
      float w0 = W0[(long)kk * Cout];
      float w1 = W1[(long)kk * Cout];
      float w2 = W2[(long)kk * Cout];
#pragma unroll
      for (int r = 0; r < ROWS; ++r)
        acc[r] += w0 * sx[r][kk] + w1 * st1[r][kk] + w2 * st2[r][kk];
    }
    __syncthreads();
  }

  if (o < Cout) {
    float bb = B[o];
    for (int r = 0; r < ROWS; ++r) {
      int i = r0 + r;
      if (i < n) {
        float v = acc[r] + bb;
        if (doRelu) v = fmaxf(v, 0.f);
        OUT[(long)i * Cout + o] = v;
      }
    }
  }
}

// X = [ hexup(h, up) | skip ] ; rows < nprev copy h, rest average two parents.
__global__ void k_upcat(const float* __restrict__ h, const int* __restrict__ up,
                        const float* __restrict__ skip,
                        int nprev, int n, int Ch, int Cs, float* __restrict__ X) {
  int Ctot = Ch + Cs;
  int total = n * Ctot;
  for (int idx = blockIdx.x * blockDim.x + threadIdx.x; idx < total; idx += gridDim.x * blockDim.x) {
    unsigned ui = (unsigned)idx / (unsigned)Ctot;
    int i = (int)ui;
    int c = idx - i * Ctot;
    float v;
    if (c < Ch) {
      if (i < nprev) {
        v = h[(long)i * Ch + c];
      } else {
        int j = i - nprev;
        int u0 = up[2 * j], u1 = up[2 * j + 1];
        v = 0.5f * (h[(long)u0 * Ch + c] + h[(long)u1 * Ch + c]);
      }
    } else {
      v = skip[(long)i * Cs + (c - Ch)];
    }
    X[idx] = v;
  }
}

// one wave (64 lanes) per row, C <= 64
__global__ void k_softmax(const float* __restrict__ A, float* __restrict__ out, int n, int C) {
  int wid = (blockIdx.x * blockDim.x + threadIdx.x) >> 6;
  int lane = threadIdx.x & 63;
  if (wid >= n) return;
  float v = (lane < C) ? A[(long)wid * C + lane] : -1e30f;
  float m = v;
  for (int s = 32; s > 0; s >>= 1) m = fmaxf(m, __shfl_xor(m, s));
  float e = (lane < C) ? __expf(v - m) : 0.f;
  float sum = e;
  for (int s = 32; s > 0; s >>= 1) sum += __shfl_xor(sum, s);
  if (lane < C) out[(long)wid * C + lane] = e / sum;
}

extern "C" void kernel_launch(void* const* d_in, const int* in_sizes, int n_in,
                              void* d_out, int out_size, void* d_ws, size_t ws_size,
                              hipStream_t stream) {
  static const int NV[6] = {42, 162, 642, 2562, 10242, 40962};
  static const int NE[6] = {240, 960, 3840, 15360, 61440, 245760};
  const int NT = 42 + 162 + 642 + 2562 + 10242 + 40962;  // 54612
  const int ET = 240 + 960 + 3840 + 15360 + 61440 + 245760;  // 327600

  EdgeParams ep;
  {
    int nb = 0, eb = 0;
    for (int l = 0; l < 6; ++l) {
      ep.e[l] = (const int*)d_in[1 + l];
      ep.E[l] = NE[l];
      ep.ebase[l] = eb;
      ep.nbase[l] = nb;
      eb += NE[l];
      nb += NV[l];
    }
  }
  const float* x0f = (const float*)d_in[0];
  const int* up[5];
  for (int i = 0; i < 5; ++i) up[i] = (const int*)d_in[7 + i];  // up2..up6
  const float *W[11], *Bb[11];
  for (int i = 0; i < 11; ++i) {
    W[i] = (const float*)d_in[12 + 2 * i];
    Bb[i] = (const float*)d_in[13 + 2 * i];
  }

  // ---- workspace carve (~45 MB total) ----
  char* p = (char*)d_ws;
  auto alloc_i = [&](size_t ne) { int* r = (int*)p; p += ne * 4; return r; };
  auto alloc_f = [&](size_t ne) { float* r = (float*)p; p += ne * 4; return r; };
  int* cnt = alloc_i(NT);
  int* ell = alloc_i((size_t)NT * MAXD);
  float* dinv = alloc_f(NT);
  float* a1 = alloc_f((size_t)40962 * 32);
  float* a2 = alloc_f((size_t)10242 * 64);
  float* a3 = alloc_f((size_t)2562 * 128);
  float* a4 = alloc_f((size_t)642 * 256);
  float* a5 = alloc_f((size_t)162 * 512);
  float* a6 = alloc_f((size_t)42 * 512);
  float* X7 = alloc_f((size_t)162 * 768);
  float* a7 = alloc_f((size_t)162 * 256);
  float* X8 = alloc_f((size_t)642 * 384);
  float* a8 = alloc_f((size_t)642 * 128);
  float* X9 = alloc_f((size_t)2562 * 192);
  float* a9 = alloc_f((size_t)2562 * 64);
  float* X10 = alloc_f((size_t)10242 * 96);
  float* a10 = alloc_f((size_t)10242 * 32);
  float* X11 = alloc_f((size_t)40962 * 36);
  float* a11 = alloc_f((size_t)40962 * 37);
  float* t1 = alloc_f((size_t)40962 * 36);  // max n*Cin over all layers

  // ---- graph setup ----
  hipMemsetAsync(cnt, 0, (size_t)NT * 4, stream);
  k_fill<<<(ET + 255) / 256, 256, 0, stream>>>(ep, cnt, ell, ET);
  k_dinv<<<(NT + 255) / 256, 256, 0, stream>>>(cnt, dinv, NT);

  auto cheb = [&](const float* X, float* OUT, int lvl, int n, int Cin, int Cout,
                  const float* Wp, const float* Bp, int relu) {
    int nb = ep.nbase[lvl];
    int total = n * Cin;
    k_prop<<<(total + 255) / 256, 256, 0, stream>>>(X, t1, cnt, ell, dinv, nb, n, Cin);
    int colTiles = (Cout + 63) / 64;
    int rowTiles = (n + 7) / 8;
    k_combine<8><<<colTiles * rowTiles, 64, 0, stream>>>(X, t1, Wp, Bp, cnt, ell, dinv,
                                                         nb, n, Cin, Cout, relu, OUT);
  };

  // encoder
  cheb(x0f, a1, 5, 40962, 4, 32, W[0], Bb[0], 1);
  cheb(a1, a2, 4, 10242, 32, 64, W[1], Bb[1], 1);   // x1 = a1[:10242]
  cheb(a2, a3, 3, 2562, 64, 128, W[2], Bb[2], 1);   // x2 = a2[:2562]
  cheb(a3, a4, 2, 642, 128, 256, W[3], Bb[3], 1);   // x3 = a3[:642]
  cheb(a4, a5, 1, 162, 256, 512, W[4], Bb[4], 1);   // x4 = a4[:162]
  cheb(a5, a6, 0, 42, 512, 512, W[5], Bb[5], 1);    // x5 = a5[:42]
  // decoder
  k_upcat<<<(162 * 768 + 255) / 256, 256, 0, stream>>>(a6, up[0], a4, 42, 162, 512, 256, X7);
  cheb(X7, a7, 1, 162, 768, 256, W[6], Bb[6], 1);
  k_upcat<<<(642 * 384 + 255) / 256, 256, 0, stream>>>(a7, up[1], a3, 162, 642, 256, 128, X8);
  cheb(X8, a8, 2, 642, 384, 128, W[7], Bb[7], 1);
  k_upcat<<<(2562 * 192 + 255) / 256, 256, 0, stream>>>(a8, up[2], a2, 642, 2562, 128, 64, X9);
  cheb(X9, a9, 3, 2562, 192, 64, W[8], Bb[8], 1);
  k_upcat<<<(10242 * 96 + 255) / 256, 256, 0, stream>>>(a9, up[3], a1, 2562, 10242, 64, 32, X10);
  cheb(X10, a10, 4, 10242, 96, 32, W[9], Bb[9], 1);
  k_upcat<<<(40962 * 36 + 255) / 256, 256, 0, stream>>>(a10, up[4], x0f, 10242, 40962, 32, 4, X11);
  cheb(X11, a11, 5, 40962, 36, 37, W[10], Bb[10], 0);
  // softmax -> out
  k_softmax<<<((40962 * 64) + 255) / 256, 256, 0, stream>>>(a11, (float*)d_out, 40962, 37);
}

// Round 3
// 656.601 us; speedup vs baseline: 1.9173x; 1.9173x over previous
//
#include <hip/hip_runtime.h>
#include <hip/hip_bf16.h>

#define MAXD 32

struct EdgeParams {
  const int* e[6];
  int E[6];
  int ebase[6];
  int nbase[6];
};

// Virtual input: X = [ hexup(h, up) | skip ] when up != nullptr, else plain h.
struct VSrc {
  const float* h;
  const float* skip;
  const int* up;
  int nprev;
  int Ch;   // channels of h
  int Cs;   // channels of skip (0 if plain)
};

__device__ __forceinline__ float vload(const VSrc& s, int i, int c) {
  if (s.up) {
    if (c >= s.Ch) return s.skip[(long)i * s.Cs + (c - s.Ch)];
    if (i >= s.nprev) {
      int j = i - s.nprev;
      int u0 = s.up[2 * j], u1 = s.up[2 * j + 1];
      return 0.5f * (s.h[(long)u0 * s.Ch + c] + s.h[(long)u1 * s.Ch + c]);
    }
    return s.h[(long)i * s.Ch + c];
  }
  return s.h[(long)i * s.Ch + c];
}

// Build ELL adjacency for all 6 levels in one kernel. cnt must be zeroed.
__global__ void k_fill(EdgeParams p, int* __restrict__ cnt, int* __restrict__ ell, int ET) {
  for (int idx = blockIdx.x * blockDim.x + threadIdx.x; idx < ET; idx += gridDim.x * blockDim.x) {
    int l;
    if (idx < p.ebase[1]) l = 0;
    else if (idx < p.ebase[2]) l = 1;
    else if (idx < p.ebase[3]) l = 2;
    else if (idx < p.ebase[4]) l = 3;
    else if (idx < p.ebase[5]) l = 4;
    else l = 5;
    int e = idx - p.ebase[l];
    const int* epp = p.e[l];
    int row = epp[e];
    int col = epp[p.E[l] + e];
    int g = p.nbase[l] + row;
    int slot = atomicAdd(&cnt[g], 1);
    if (slot < MAXD) ell[g * MAXD + slot] = col;
  }
}

__global__ void k_dinv(const int* __restrict__ cnt, float* __restrict__ dinv, int NT) {
  int i = blockIdx.x * blockDim.x + threadIdx.x;
  if (i < NT) {
    int d = cnt[i];
    dinv[i] = d > 0 ? rsqrtf((float)d) : 0.0f;
  }
}

// t1[i,c] = -dinv[i] * sum_j dinv[col_j] * X[col_j, c], X virtual. 8-deep batched gather.
__global__ void k_prop(VSrc src, float* __restrict__ T,
                       const int* __restrict__ cnt, const int* __restrict__ ell,
                       const float* __restrict__ dinv, int nbase, int n, int C) {
  int total = n * C;
  for (int idx = blockIdx.x * blockDim.x + threadIdx.x; idx < total; idx += gridDim.x * blockDim.x) {
    unsigned ui = (unsigned)idx / (unsigned)C;
    int i = (int)ui;
    int c = idx - i * C;
    int g = nbase + i;
    int d = cnt[g]; if (d > MAXD) d = MAXD;
    const int* cols = ell + (long)g * MAXD;
    float acc = 0.f;
    for (int t = 0; t < d; t += 8) {
      int ci[8]; float wj[8];
#pragma unroll
      for (int j = 0; j < 8; ++j) {
        int tt = t + j;
        int cj = cols[(tt < d) ? tt : 0];
        ci[j] = cj;
        wj[j] = (tt < d) ? dinv[nbase + cj] : 0.f;
      }
#pragma unroll
      for (int j = 0; j < 8; ++j)
        acc += wj[j] * vload(src, ci[j], c);
    }
    T[idx] = -dinv[g] * acc;
  }
}

// Fused t2-gather + [X|t1|t2] @ W + b (+relu).
// 256 threads = 4 waves. CW waves split K-chunks (cross-wave LDS reduction at end),
// 4/CW wave-groups split the block's ROWS rows. Lane = output column within 64-col tile.
template <int ROWS, int CW>
__global__ __launch_bounds__(256) void k_combine(
    VSrc src, const float* __restrict__ T1,
    const float* __restrict__ W, const float* __restrict__ B,
    const int* __restrict__ cnt, const int* __restrict__ ell,
    const float* __restrict__ dinv,
    int nbase, int n, int Cin, int Cout, int doRelu,
    float* __restrict__ OUT) {
  constexpr int RW = 4 / CW;        // row groups
  constexpr int RPW = ROWS / RW;    // rows per wave

  __shared__ __align__(16) float sx[4][RPW][64];
  __shared__ __align__(16) float st1[4][RPW][64];
  __shared__ __align__(16) float st2[4][RPW][64];

  int tid = threadIdx.x;
  int w = tid >> 6;
  int lane = tid & 63;
  int rg = w / CW;
  int cw = w % CW;

  int colTiles = (Cout + 63) >> 6;
  int ct = blockIdx.x % colTiles;
  int rt = blockIdx.x / colTiles;
  int r0 = rt * ROWS + rg * RPW;
  int o = ct * 64 + lane;
  int oc = (o < Cout) ? o : (Cout - 1);
  int nch = (Cin + 63) >> 6;

  float acc[RPW];
#pragma unroll
  for (int r = 0; r < RPW; ++r) acc[r] = 0.f;

  for (int cg = 0; cg < nch; cg += CW) {
    int c = cg + cw;
    bool act = c < nch;
    int k0 = c * 64;
    int kw = act ? ((Cin - k0 < 64) ? (Cin - k0) : 64) : 0;
    int k = k0 + lane;
    bool kv = act && (lane < kw);

    // stage x, t1 and compute t2 via gather
#pragma unroll
    for (int rr = 0; rr < RPW; ++rr) {
      int i = r0 + rr;
      bool iv = i < n;
      float xv = 0.f, tv = 0.f, t2v = 0.f;
      if (kv && iv) {
        xv = vload(src, i, k);
        tv = T1[(long)i * Cin + k];
        int g = nbase + i;
        int d = cnt[g]; if (d > MAXD) d = MAXD;
        const int* cols = ell + (long)g * MAXD;
        float a2 = 0.f;
        for (int t = 0; t < d; t += 8) {
          int ci[8]; float wj[8];
#pragma unroll
          for (int j = 0; j < 8; ++j) {
            int tt = t + j;
            int cj = cols[(tt < d) ? tt : 0];
            ci[j] = cj;
            wj[j] = (tt < d) ? dinv[nbase + cj] : 0.f;
          }
#pragma unroll
          for (int j = 0; j < 8; ++j)
            a2 += wj[j] * T1[(long)ci[j] * Cin + k];
        }
        t2v = -2.f * dinv[g] * a2 - xv;
      }
      sx[w][rr][lane] = xv;
      st1[w][rr][lane] = tv;
      st2[w][rr][lane] = t2v;
    }
    __syncthreads();

    // matmul over this wave's chunk (kw % 4 == 0 for all layer shapes here)
    int kw4 = kw >> 2;
    long ts = (long)Cin * Cout;
    for (int q = 0; q < kw4; ++q) {
      float w0[4], w1[4], w2[4];
#pragma unroll
      for (int j = 0; j < 4; ++j) {
        long off = (long)(k0 + q * 4 + j) * Cout + oc;
        w0[j] = W[off];
        w1[j] = W[ts + off];
        w2[j] = W[2 * ts + off];
      }
#pragma unroll
      for (int rr = 0; rr < RPW; ++rr) {
        float4 xs = ((const float4*)sx[w][rr])[q];
        float4 t1s = ((const float4*)st1[w][rr])[q];
        float4 t2s = ((const float4*)st2[w][rr])[q];
        acc[rr] += w0[0] * xs.x + w0[1] * xs.y + w0[2] * xs.z + w0[3] * xs.w;
        acc[rr] += w1[0] * t1s.x + w1[1] * t1s.y + w1[2] * t1s.z + w1[3] * t1s.w;
        acc[rr] += w2[0] * t2s.x + w2[1] * t2s.y + w2[2] * t2s.z + w2[3] * t2s.w;
      }
    }
    __syncthreads();
  }

  if (CW == 1) {
    if (o < Cout) {
      float bb = B[oc];
#pragma unroll
      for (int rr = 0; rr < RPW; ++rr) {
        int i = r0 + rr;
        if (i < n) {
          float v = acc[rr] + bb;
          if (doRelu) v = fmaxf(v, 0.f);
          OUT[(long)i * Cout + o] = v;
        }
      }
    }
  } else {
    // cross-wave K reduction: reuse sx
#pragma unroll
    for (int rr = 0; rr < RPW; ++rr) sx[w][rr][lane] = acc[rr];
    __syncthreads();
    if (cw == 0 && o < Cout) {
      float bb = B[oc];
#pragma unroll
      for (int rr = 0; rr < RPW; ++rr) {
        int i = r0 + rr;
        if (i < n) {
          float v = bb;
#pragma unroll
          for (int j = 0; j < CW; ++j) v += sx[rg * CW + j][rr][lane];
          if (doRelu) v = fmaxf(v, 0.f);
          OUT[(long)i * Cout + o] = v;
        }
      }
    }
  }
}

// one wave (64 lanes) per row, C <= 64
__global__ void k_softmax(const float* __restrict__ A, float* __restrict__ out, int n, int C) {
  int wid = (blockIdx.x * blockDim.x + threadIdx.x) >> 6;
  int lane = threadIdx.x & 63;
  if (wid >= n) return;
  float v = (lane < C) ? A[(long)wid * C + lane] : -1e30f;
  float m = v;
  for (int s = 32; s > 0; s >>= 1) m = fmaxf(m, __shfl_xor(m, s));
  float e = (lane < C) ? __expf(v - m) : 0.f;
  float sum = e;
  for (int s = 32; s > 0; s >>= 1) sum += __shfl_xor(sum, s);
  if (lane < C) out[(long)wid * C + lane] = e / sum;
}

extern "C" void kernel_launch(void* const* d_in, const int* in_sizes, int n_in,
                              void* d_out, int out_size, void* d_ws, size_t ws_size,
                              hipStream_t stream) {
  static const int NV[6] = {42, 162, 642, 2562, 10242, 40962};
  static const int NE[6] = {240, 960, 3840, 15360, 61440, 245760};
  const int NT = 54612;
  const int ET = 327600;

  EdgeParams ep;
  {
    int nb = 0, eb = 0;
    for (int l = 0; l < 6; ++l) {
      ep.e[l] = (const int*)d_in[1 + l];
      ep.E[l] = NE[l];
      ep.ebase[l] = eb;
      ep.nbase[l] = nb;
      eb += NE[l];
      nb += NV[l];
    }
  }
  const float* x0f = (const float*)d_in[0];
  const int* up[5];
  for (int i = 0; i < 5; ++i) up[i] = (const int*)d_in[7 + i];  // up2..up6
  const float *W[11], *Bb[11];
  for (int i = 0; i < 11; ++i) {
    W[i] = (const float*)d_in[12 + 2 * i];
    Bb[i] = (const float*)d_in[13 + 2 * i];
  }

  // ---- workspace carve ----
  char* p = (char*)d_ws;
  auto alloc_i = [&](size_t ne) { int* r = (int*)p; p += ne * 4; return r; };
  auto alloc_f = [&](size_t ne) { float* r = (float*)p; p += ne * 4; return r; };
  int* cnt = alloc_i(NT);
  int* ell = alloc_i((size_t)NT * MAXD);
  float* dinv = alloc_f(NT);
  float* a1 = alloc_f((size_t)40962 * 32);
  float* a2 = alloc_f((size_t)10242 * 64);
  float* a3 = alloc_f((size_t)2562 * 128);
  float* a4 = alloc_f((size_t)642 * 256);
  float* a5 = alloc_f((size_t)162 * 512);
  float* a6 = alloc_f((size_t)42 * 512);
  float* a7 = alloc_f((size_t)162 * 256);
  float* a8 = alloc_f((size_t)642 * 128);
  float* a9 = alloc_f((size_t)2562 * 64);
  float* a10 = alloc_f((size_t)10242 * 32);
  float* a11 = alloc_f((size_t)40962 * 37);
  float* t1 = alloc_f((size_t)40962 * 36);  // max n*Cin over all layers

  hipMemsetAsync(cnt, 0, (size_t)NT * 4, stream);
  k_fill<<<(ET + 255) / 256, 256, 0, stream>>>(ep, cnt, ell, ET);
  k_dinv<<<(NT + 255) / 256, 256, 0, stream>>>(cnt, dinv, NT);

  auto cheb = [&](VSrc src, float* OUT, int lvl, int n, int Cin, int Cout,
                  const float* Wp, const float* Bp, int relu, int rows, int cwv) {
    int nb = ep.nbase[lvl];
    int total = n * Cin;
    k_prop<<<(total + 255) / 256, 256, 0, stream>>>(src, t1, cnt, ell, dinv, nb, n, Cin);
    int colTiles = (Cout + 63) / 64;
    int rowTiles = (n + rows - 1) / rows;
    dim3 grid(colTiles * rowTiles);
    if (rows == 8 && cwv == 1)
      k_combine<8, 1><<<grid, 256, 0, stream>>>(src, t1, Wp, Bp, cnt, ell, dinv, nb, n, Cin, Cout, relu, OUT);
    else if (rows == 8 && cwv == 2)
      k_combine<8, 2><<<grid, 256, 0, stream>>>(src, t1, Wp, Bp, cnt, ell, dinv, nb, n, Cin, Cout, relu, OUT);
    else
      k_combine<4, 4><<<grid, 256, 0, stream>>>(src, t1, Wp, Bp, cnt, ell, dinv, nb, n, Cin, Cout, relu, OUT);
  };

  auto plain = [](const float* h, int Ch) { VSrc s{h, nullptr, nullptr, 0, Ch, 0}; return s; };
  auto upsrc = [](const float* h, const float* sk, const int* u, int nprev, int Ch, int Cs) {
    VSrc s{h, sk, u, nprev, Ch, Cs}; return s;
  };

  // encoder
  cheb(plain(x0f, 4), a1, 5, 40962, 4, 32, W[0], Bb[0], 1, 8, 1);
  cheb(plain(a1, 32), a2, 4, 10242, 32, 64, W[1], Bb[1], 1, 8, 1);   // x1 = a1[:10242]
  cheb(plain(a2, 64), a3, 3, 2562, 64, 128, W[2], Bb[2], 1, 8, 1);   // x2 = a2[:2562]
  cheb(plain(a3, 128), a4, 2, 642, 128, 256, W[3], Bb[3], 1, 8, 2);  // x3 = a3[:642]
  cheb(plain(a4, 256), a5, 1, 162, 256, 512, W[4], Bb[4], 1, 4, 4);  // x4 = a4[:162]
  cheb(plain(a5, 512), a6, 0, 42, 512, 512, W[5], Bb[5], 1, 4, 4);   // x5 = a5[:42]
  // decoder (upcat fused via VSrc)
  cheb(upsrc(a6, a4, up[0], 42, 512, 256), a7, 1, 162, 768, 256, W[6], Bb[6], 1, 4, 4);
  cheb(upsrc(a7, a3, up[1], 162, 256, 128), a8, 2, 642, 384, 128, W[7], Bb[7], 1, 4, 4);
  cheb(upsrc(a8, a2, up[2], 642, 128, 64), a9, 3, 2562, 192, 64, W[8], Bb[8], 1, 8, 2);
  cheb(upsrc(a9, a1, up[3], 2562, 64, 32), a10, 4, 10242, 96, 32, W[9], Bb[9], 1, 8, 2);
  cheb(upsrc(a10, x0f, up[4], 10242, 32, 4), a11, 5, 40962, 36, 37, W[10], Bb[10], 0, 8, 1);
  // softmax -> out
  k_softmax<<<((40962 * 64) + 255) / 256, 256, 0, stream>>>(a11, (float*)d_out, 40962, 37);
}

// Round 4
// 580.254 us; speedup vs baseline: 2.1696x; 1.1316x over previous
//
#include <hip/hip_runtime.h>
#include <hip/hip_bf16.h>

#define MAXD 32
typedef __hip_bfloat16 bf16;

__device__ __forceinline__ float bf2f(bf16 v) { return __bfloat162float(v); }
__device__ __forceinline__ float2 ldbf2(const bf16* p) {  // 2 consecutive bf16, 4B-aligned
  unsigned u = *(const unsigned*)p;
  return make_float2(__uint_as_float(u << 16), __uint_as_float(u & 0xffff0000u));
}

struct EdgeParams {
  const int* e[6];
  int E[6];
  int ebase[6];
  int nbase[6];
};

// Virtual input: X = [ hexup(h, up) | skip ] when up != nullptr, else plain h.
// fp32 pointers for dense/staging reads, bf16 shadows for gathers.
struct VSrc {
  const float* hf; const bf16* hh;
  const float* skf; const bf16* skh;
  const int* up;
  int nprev, Ch, Cs;  // Ch, Cs always even
};

__device__ __forceinline__ float vloadf(const VSrc& s, int i, int c) {
  if (s.up) {
    if (c >= s.Ch) return s.skf[(long)i * s.Cs + (c - s.Ch)];
    if (i >= s.nprev) {
      int j = i - s.nprev;
      int u0 = s.up[2 * j], u1 = s.up[2 * j + 1];
      return 0.5f * (s.hf[(long)u0 * s.Ch + c] + s.hf[(long)u1 * s.Ch + c]);
    }
    return s.hf[(long)i * s.Ch + c];
  }
  return s.hf[(long)i * s.Ch + c];
}

// bf16 pair load of channels (2*c2, 2*c2+1); Ch,Cs even so pairs never straddle.
__device__ __forceinline__ float2 vloadh2(const VSrc& s, int i, int c2) {
  int c = 2 * c2;
  if (s.up) {
    if (c >= s.Ch) return ldbf2(s.skh + (long)i * s.Cs + (c - s.Ch));
    if (i >= s.nprev) {
      int j = i - s.nprev;
      int u0 = s.up[2 * j], u1 = s.up[2 * j + 1];
      float2 a = ldbf2(s.hh + (long)u0 * s.Ch + c);
      float2 b = ldbf2(s.hh + (long)u1 * s.Ch + c);
      return make_float2(0.5f * (a.x + b.x), 0.5f * (a.y + b.y));
    }
    return ldbf2(s.hh + (long)i * s.Ch + c);
  }
  return ldbf2(s.hh + (long)i * s.Ch + c);
}

// Build ELL adjacency (col only) for all 6 levels. cnt must be zeroed.
__global__ void k_fill(EdgeParams p, int* __restrict__ cnt, int2* __restrict__ ell, int ET) {
  for (int idx = blockIdx.x * blockDim.x + threadIdx.x; idx < ET; idx += gridDim.x * blockDim.x) {
    int l;
    if (idx < p.ebase[1]) l = 0;
    else if (idx < p.ebase[2]) l = 1;
    else if (idx < p.ebase[3]) l = 2;
    else if (idx < p.ebase[4]) l = 3;
    else if (idx < p.ebase[5]) l = 4;
    else l = 5;
    int e = idx - p.ebase[l];
    const int* epp = p.e[l];
    int row = epp[e];
    int col = epp[p.E[l] + e];
    int g = p.nbase[l] + row;
    int slot = atomicAdd(&cnt[g], 1);
    if (slot < MAXD) ell[g * MAXD + slot].x = col;
  }
}

// Fill .y = bitcast(-dinv[row]*dinv[col]) for valid slots.
__global__ void k_wfill(EdgeParams p, const int* __restrict__ cnt, int2* __restrict__ ell, int NT) {
  int total = NT * MAXD;
  for (int idx = blockIdx.x * blockDim.x + threadIdx.x; idx < total; idx += gridDim.x * blockDim.x) {
    int g = idx >> 5;
    int t = idx & (MAXD - 1);
    int dg = cnt[g];
    int d = dg < MAXD ? dg : MAXD;
    if (t < d) {
      int l;
      if (g < p.nbase[1]) l = 0;
      else if (g < p.nbase[2]) l = 1;
      else if (g < p.nbase[3]) l = 2;
      else if (g < p.nbase[4]) l = 3;
      else if (g < p.nbase[5]) l = 4;
      else l = 5;
      int c = ell[idx].x;
      int dc = cnt[p.nbase[l] + c];
      float w = (dc > 0) ? -(rsqrtf((float)dg) * rsqrtf((float)dc)) : 0.0f;
      ell[idx].y = __float_as_int(w);
    }
  }
}

__global__ void k_cvt(const float* __restrict__ in, bf16* __restrict__ out, int N) {
  for (int i = blockIdx.x * blockDim.x + threadIdx.x; i < N; i += gridDim.x * blockDim.x)
    out[i] = __float2bfloat16(in[i]);
}

// t1[i,:] = sum_t w_t * X[col_t,:]  (w carries the minus sign). Pair-per-thread.
__global__ void k_prop(VSrc src, float* __restrict__ T, bf16* __restrict__ Th,
                       const int* __restrict__ cnt, const int2* __restrict__ ell,
                       int nbase, int n, int C) {
  int C2 = C >> 1;
  int total = n * C2;
  for (int idx = blockIdx.x * blockDim.x + threadIdx.x; idx < total; idx += gridDim.x * blockDim.x) {
    int i = idx / C2;
    int c2 = idx - i * C2;
    int g = nbase + i;
    int d = cnt[g]; if (d > MAXD) d = MAXD;
    const int2* cols = ell + (long)g * MAXD;
    float ax = 0.f, ay = 0.f;
    for (int t = 0; t < d; t += 8) {
      int ci[8]; float wj[8];
#pragma unroll
      for (int j = 0; j < 8; ++j) {
        int tt = t + j;
        int2 e = cols[(tt < d) ? tt : 0];
        ci[j] = e.x;
        wj[j] = (tt < d) ? __int_as_float(e.y) : 0.f;
      }
#pragma unroll
      for (int j = 0; j < 8; ++j) {
        float2 v = vloadh2(src, ci[j], c2);
        ax += wj[j] * v.x;
        ay += wj[j] * v.y;
      }
    }
    long o = (long)i * C + 2 * c2;
    ((float2*)T)[o >> 1] = make_float2(ax, ay);
    Th[o] = __float2bfloat16(ax);
    Th[o + 1] = __float2bfloat16(ay);
  }
}

// Fused t2-gather + [X|t1|t2] @ W + b (+relu / +softmax).
// 256 threads = 4 waves. CW waves split K-chunks, 4/CW groups split rows.
template <int ROWS, int CW, int SMAX>
__global__ __launch_bounds__(256) void k_combine(
    VSrc src, const float* __restrict__ T1, const bf16* __restrict__ T1h,
    const float* __restrict__ W, const float* __restrict__ B,
    const int* __restrict__ cnt, const int2* __restrict__ ell,
    int nbase, int n, int Cin, int Cout, int doRelu,
    float* __restrict__ OUT, bf16* __restrict__ OUTh) {
  constexpr int RW = 4 / CW;
  constexpr int RPW = ROWS / RW;

  __shared__ __align__(16) float sx[4][RPW][64];
  __shared__ __align__(16) float st1[4][RPW][64];
  __shared__ __align__(16) float st2[4][RPW][64];

  int tid = threadIdx.x;
  int w = tid >> 6;
  int lane = tid & 63;
  int rg = w / CW;
  int cw = w % CW;

  int colTiles = (Cout + 63) >> 6;
  int ct = blockIdx.x % colTiles;
  int rt = blockIdx.x / colTiles;
  int r0 = rt * ROWS + rg * RPW;
  int o = ct * 64 + lane;
  int oc = (o < Cout) ? o : (Cout - 1);
  int nch = (Cin + 63) >> 6;

  float acc[RPW];
#pragma unroll
  for (int r = 0; r < RPW; ++r) acc[r] = 0.f;

  for (int cg = 0; cg < nch; cg += CW) {
    int c = cg + cw;
    bool act = c < nch;
    int k0 = c * 64;
    int kw = act ? ((Cin - k0 < 64) ? (Cin - k0) : 64) : 0;
    int k = k0 + lane;
    bool kv = act && (lane < kw);

#pragma unroll
    for (int rr = 0; rr < RPW; ++rr) {
      int i = r0 + rr;
      bool iv = i < n;
      float xv = 0.f, tv = 0.f, t2v = 0.f;
      if (kv && iv) {
        xv = vloadf(src, i, k);
        tv = T1[(long)i * Cin + k];
        int g = nbase + i;
        int d = cnt[g]; if (d > MAXD) d = MAXD;
        const int2* cols = ell + (long)g * MAXD;
        float a2 = 0.f;
        for (int t = 0; t < d; t += 8) {
          int ci[8]; float wj[8];
#pragma unroll
          for (int j = 0; j < 8; ++j) {
            int tt = t + j;
            int2 e = cols[(tt < d) ? tt : 0];
            ci[j] = e.x;
            wj[j] = (tt < d) ? __int_as_float(e.y) : 0.f;
          }
#pragma unroll
          for (int j = 0; j < 8; ++j)
            a2 += wj[j] * bf2f(T1h[(long)ci[j] * Cin + k]);
        }
        t2v = 2.f * a2 - xv;
      }
      sx[w][rr][lane] = xv;
      st1[w][rr][lane] = tv;
      st2[w][rr][lane] = t2v;
    }
    __syncthreads();

    int kw4 = kw >> 2;
    long ts = (long)Cin * Cout;
    for (int q = 0; q < kw4; ++q) {
      float w0[4], w1[4], w2[4];
#pragma unroll
      for (int j = 0; j < 4; ++j) {
        long off = (long)(k0 + q * 4 + j) * Cout + oc;
        w0[j] = W[off];
        w1[j] = W[ts + off];
        w2[j] = W[2 * ts + off];
      }
#pragma unroll
      for (int rr = 0; rr < RPW; ++rr) {
        float4 xs = ((const float4*)sx[w][rr])[q];
        float4 t1s = ((const float4*)st1[w][rr])[q];
        float4 t2s = ((const float4*)st2[w][rr])[q];
        acc[rr] += w0[0] * xs.x + w0[1] * xs.y + w0[2] * xs.z + w0[3] * xs.w;
        acc[rr] += w1[0] * t1s.x + w1[1] * t1s.y + w1[2] * t1s.z + w1[3] * t1s.w;
        acc[rr] += w2[0] * t2s.x + w2[1] * t2s.y + w2[2] * t2s.z + w2[3] * t2s.w;
      }
    }
    __syncthreads();
  }

  if constexpr (SMAX) {
    // CW==1, colTiles==1: each wave holds complete logit rows -> softmax in-wave.
    float bb = (o < Cout) ? B[o] : 0.f;
#pragma unroll
    for (int rr = 0; rr < RPW; ++rr) {
      int i = r0 + rr;
      if (i < n) {
        float v = (o < Cout) ? (acc[rr] + bb) : -1e30f;
        float m = v;
        for (int s = 32; s > 0; s >>= 1) m = fmaxf(m, __shfl_xor(m, s));
        float e = (o < Cout) ? __expf(v - m) : 0.f;
        float sum = e;
        for (int s = 32; s > 0; s >>= 1) sum += __shfl_xor(sum, s);
        if (o < Cout) OUT[(long)i * Cout + o] = e / sum;
      }
    }
  } else if constexpr (CW == 1) {
    if (o < Cout) {
      float bb = B[oc];
#pragma unroll
      for (int rr = 0; rr < RPW; ++rr) {
        int i = r0 + rr;
        if (i < n) {
          float v = acc[rr] + bb;
          if (doRelu) v = fmaxf(v, 0.f);
          long off = (long)i * Cout + o;
          OUT[off] = v;
          OUTh[off] = __float2bfloat16(v);
        }
      }
    }
  } else {
#pragma unroll
    for (int rr = 0; rr < RPW; ++rr) sx[w][rr][lane] = acc[rr];
    __syncthreads();
    if (cw == 0 && o < Cout) {
      float bb = B[oc];
#pragma unroll
      for (int rr = 0; rr < RPW; ++rr) {
        int i = r0 + rr;
        if (i < n) {
          float v = bb;
#pragma unroll
          for (int j = 0; j < CW; ++j) v += sx[rg * CW + j][rr][lane];
          if (doRelu) v = fmaxf(v, 0.f);
          long off = (long)i * Cout + o;
          OUT[off] = v;
          OUTh[off] = __float2bfloat16(v);
        }
      }
    }
  }
}

extern "C" void kernel_launch(void* const* d_in, const int* in_sizes, int n_in,
                              void* d_out, int out_size, void* d_ws, size_t ws_size,
                              hipStream_t stream) {
  static const int NV[6] = {42, 162, 642, 2562, 10242, 40962};
  static const int NE[6] = {240, 960, 3840, 15360, 61440, 245760};
  const int NT = 54612;
  const int ET = 327600;

  EdgeParams ep;
  {
    int nb = 0, eb = 0;
    for (int l = 0; l < 6; ++l) {
      ep.e[l] = (const int*)d_in[1 + l];
      ep.E[l] = NE[l];
      ep.ebase[l] = eb;
      ep.nbase[l] = nb;
      eb += NE[l];
      nb += NV[l];
    }
  }
  const float* x0f = (const float*)d_in[0];
  const int* up[5];
  for (int i = 0; i < 5; ++i) up[i] = (const int*)d_in[7 + i];  // up2..up6
  const float *W[11], *Bb[11];
  for (int i = 0; i < 11; ++i) {
    W[i] = (const float*)d_in[12 + 2 * i];
    Bb[i] = (const float*)d_in[13 + 2 * i];
  }

  // ---- workspace carve (16B-aligned blocks) ----
  char* p = (char*)d_ws;
  auto alloc_b = [&](size_t bytes) { void* r = (void*)p; p += (bytes + 15) & ~size_t(15); return r; };
  auto alloc_i = [&](size_t ne) { return (int*)alloc_b(ne * 4); };
  auto alloc_f = [&](size_t ne) { return (float*)alloc_b(ne * 4); };
  auto alloc_h = [&](size_t ne) { return (bf16*)alloc_b(ne * 2); };
  int* cnt = alloc_i(NT);
  int2* ell = (int2*)alloc_b((size_t)NT * MAXD * 8);
  float* t1f = alloc_f((size_t)40962 * 36);
  bf16* t1h = alloc_h((size_t)40962 * 36);
  bf16* x0h = alloc_h((size_t)40962 * 4);
  float *af[11]; bf16 *ah[11];
  const int an[11] = {40962, 10242, 2562, 642, 162, 42, 162, 642, 2562, 10242, 0};
  const int ac[11] = {32, 64, 128, 256, 512, 512, 256, 128, 64, 32, 0};
  for (int i = 0; i < 10; ++i) {
    af[i] = alloc_f((size_t)an[i] * ac[i]);
    ah[i] = alloc_h((size_t)an[i] * ac[i]);
  }

  hipMemsetAsync(cnt, 0, (size_t)NT * 4, stream);
  k_fill<<<(ET + 255) / 256, 256, 0, stream>>>(ep, cnt, ell, ET);
  k_wfill<<<(NT * MAXD + 255) / 256, 256, 0, stream>>>(ep, cnt, ell, NT);
  k_cvt<<<(40962 * 4 + 255) / 256, 256, 0, stream>>>(x0f, x0h, 40962 * 4);

  auto cheb = [&](VSrc src, float* OUT, bf16* OUTh, int lvl, int n, int Cin, int Cout,
                  const float* Wp, const float* Bp, int relu, int rows, int cwv, int smax) {
    int nb = ep.nbase[lvl];
    int total2 = n * (Cin >> 1);
    k_prop<<<(total2 + 255) / 256, 256, 0, stream>>>(src, t1f, t1h, cnt, ell, nb, n, Cin);
    int colTiles = (Cout + 63) / 64;
    int rowTiles = (n + rows - 1) / rows;
    dim3 grid(colTiles * rowTiles);
    if (smax)
      k_combine<8, 1, 1><<<grid, 256, 0, stream>>>(src, t1f, t1h, Wp, Bp, cnt, ell, nb, n, Cin, Cout, relu, OUT, OUTh);
    else if (rows == 8 && cwv == 1)
      k_combine<8, 1, 0><<<grid, 256, 0, stream>>>(src, t1f, t1h, Wp, Bp, cnt, ell, nb, n, Cin, Cout, relu, OUT, OUTh);
    else if (rows == 8 && cwv == 2)
      k_combine<8, 2, 0><<<grid, 256, 0, stream>>>(src, t1f, t1h, Wp, Bp, cnt, ell, nb, n, Cin, Cout, relu, OUT, OUTh);
    else
      k_combine<4, 4, 0><<<grid, 256, 0, stream>>>(src, t1f, t1h, Wp, Bp, cnt, ell, nb, n, Cin, Cout, relu, OUT, OUTh);
  };

  auto plain = [](const float* hf, const bf16* hh, int Ch) {
    VSrc s{hf, hh, nullptr, nullptr, nullptr, 0, Ch, 0}; return s;
  };
  auto upsrc = [](const float* hf, const bf16* hh, const float* skf, const bf16* skh,
                  const int* u, int nprev, int Ch, int Cs) {
    VSrc s{hf, hh, skf, skh, u, nprev, Ch, Cs}; return s;
  };

  // encoder
  cheb(plain(x0f, x0h, 4), af[0], ah[0], 5, 40962, 4, 32, W[0], Bb[0], 1, 8, 1, 0);
  cheb(plain(af[0], ah[0], 32), af[1], ah[1], 4, 10242, 32, 64, W[1], Bb[1], 1, 8, 1, 0);
  cheb(plain(af[1], ah[1], 64), af[2], ah[2], 3, 2562, 64, 128, W[2], Bb[2], 1, 8, 1, 0);
  cheb(plain(af[2], ah[2], 128), af[3], ah[3], 2, 642, 128, 256, W[3], Bb[3], 1, 8, 2, 0);
  cheb(plain(af[3], ah[3], 256), af[4], ah[4], 1, 162, 256, 512, W[4], Bb[4], 1, 4, 4, 0);
  cheb(plain(af[4], ah[4], 512), af[5], ah[5], 0, 42, 512, 512, W[5], Bb[5], 1, 4, 4, 0);
  // decoder (upcat fused via VSrc)
  cheb(upsrc(af[5], ah[5], af[3], ah[3], up[0], 42, 512, 256), af[6], ah[6], 1, 162, 768, 256, W[6], Bb[6], 1, 4, 4, 0);
  cheb(upsrc(af[6], ah[6], af[2], ah[2], up[1], 162, 256, 128), af[7], ah[7], 2, 642, 384, 128, W[7], Bb[7], 1, 4, 4, 0);
  cheb(upsrc(af[7], ah[7], af[1], ah[1], up[2], 642, 128, 64), af[8], ah[8], 3, 2562, 192, 64, W[8], Bb[8], 1, 8, 2, 0);
  cheb(upsrc(af[8], ah[8], af[0], ah[0], up[3], 2562, 64, 32), af[9], ah[9], 4, 10242, 96, 32, W[9], Bb[9], 1, 8, 2, 0);
  // final layer: softmax fused, writes d_out directly
  cheb(upsrc(af[9], ah[9], x0f, x0h, up[4], 10242, 32, 4), (float*)d_out, nullptr, 5, 40962, 36, 37, W[10], Bb[10], 0, 8, 1, 1);
}

// Round 5
// 551.460 us; speedup vs baseline: 2.2829x; 1.0522x over previous
//
#include <hip/hip_runtime.h>
#include <hip/hip_bf16.h>

#define MAXD 32
typedef __hip_bfloat16 bf16;

__device__ __forceinline__ float bf2f(bf16 v) { return __bfloat162float(v); }
__device__ __forceinline__ float2 ldbf2(const bf16* p) {  // 2 consecutive bf16, 4B-aligned
  unsigned u = *(const unsigned*)p;
  return make_float2(__uint_as_float(u << 16), __uint_as_float(u & 0xffff0000u));
}
__device__ __forceinline__ float2 unpk(unsigned u) {
  return make_float2(__uint_as_float(u << 16), __uint_as_float(u & 0xffff0000u));
}
__device__ __forceinline__ unsigned pk2(float x, float y) {
  bf16 bx = __float2bfloat16(x), by = __float2bfloat16(y);
  unsigned short ux, uy;
  __builtin_memcpy(&ux, &bx, 2);
  __builtin_memcpy(&uy, &by, 2);
  return (unsigned)ux | ((unsigned)uy << 16);
}

struct EdgeParams {
  const int* e[6];
  int E[6];
  int ebase[6];
  int nbase[6];
};

// Virtual input: X = [ hexup(h, up) | skip ] when up != nullptr, else plain h.
struct VSrc {
  const float* hf; const bf16* hh;
  const float* skf; const bf16* skh;
  const int* up;
  int nprev, Ch, Cs;  // Ch, Cs always even
};

__device__ __forceinline__ float vloadf(const VSrc& s, int i, int c) {
  if (s.up) {
    if (c >= s.Ch) return s.skf[(long)i * s.Cs + (c - s.Ch)];
    if (i >= s.nprev) {
      int j = i - s.nprev;
      int u0 = s.up[2 * j], u1 = s.up[2 * j + 1];
      return 0.5f * (s.hf[(long)u0 * s.Ch + c] + s.hf[(long)u1 * s.Ch + c]);
    }
    return s.hf[(long)i * s.Ch + c];
  }
  return s.hf[(long)i * s.Ch + c];
}

__device__ __forceinline__ float2 vloadh2(const VSrc& s, int i, int c2) {
  int c = 2 * c2;
  if (s.up) {
    if (c >= s.Ch) return ldbf2(s.skh + (long)i * s.Cs + (c - s.Ch));
    if (i >= s.nprev) {
      int j = i - s.nprev;
      int u0 = s.up[2 * j], u1 = s.up[2 * j + 1];
      float2 a = ldbf2(s.hh + (long)u0 * s.Ch + c);
      float2 b = ldbf2(s.hh + (long)u1 * s.Ch + c);
      return make_float2(0.5f * (a.x + b.x), 0.5f * (a.y + b.y));
    }
    return ldbf2(s.hh + (long)i * s.Ch + c);
  }
  return ldbf2(s.hh + (long)i * s.Ch + c);
}

// Build ELL adjacency (col only) for all 6 levels. cnt must be zeroed.
__global__ void k_fill(EdgeParams p, int* __restrict__ cnt, int2* __restrict__ ell, int ET) {
  for (int idx = blockIdx.x * blockDim.x + threadIdx.x; idx < ET; idx += gridDim.x * blockDim.x) {
    int l;
    if (idx < p.ebase[1]) l = 0;
    else if (idx < p.ebase[2]) l = 1;
    else if (idx < p.ebase[3]) l = 2;
    else if (idx < p.ebase[4]) l = 3;
    else if (idx < p.ebase[5]) l = 4;
    else l = 5;
    int e = idx - p.ebase[l];
    const int* epp = p.e[l];
    int row = epp[e];
    int col = epp[p.E[l] + e];
    int g = p.nbase[l] + row;
    int slot = atomicAdd(&cnt[g], 1);
    if (slot < MAXD) ell[g * MAXD + slot].x = col;
  }
}

// Fill .y = bitcast(-dinv[row]*dinv[col]) for valid slots.
__global__ void k_wfill(EdgeParams p, const int* __restrict__ cnt, int2* __restrict__ ell, int NT) {
  int total = NT * MAXD;
  for (int idx = blockIdx.x * blockDim.x + threadIdx.x; idx < total; idx += gridDim.x * blockDim.x) {
    int g = idx >> 5;
    int t = idx & (MAXD - 1);
    int dg = cnt[g];
    int d = dg < MAXD ? dg : MAXD;
    if (t < d) {
      int l;
      if (g < p.nbase[1]) l = 0;
      else if (g < p.nbase[2]) l = 1;
      else if (g < p.nbase[3]) l = 2;
      else if (g < p.nbase[4]) l = 3;
      else if (g < p.nbase[5]) l = 4;
      else l = 5;
      int c = ell[idx].x;
      int dc = cnt[p.nbase[l] + c];
      float w = (dc > 0) ? -(rsqrtf((float)dg) * rsqrtf((float)dc)) : 0.0f;
      ell[idx].y = __float_as_int(w);
    }
  }
}

__global__ void k_cvt(const float* __restrict__ in, bf16* __restrict__ out, int N) {
  for (int i = blockIdx.x * blockDim.x + threadIdx.x; i < N; i += gridDim.x * blockDim.x)
    out[i] = __float2bfloat16(in[i]);
}

// Materialize virtual upcat source into flat bf16 (pair per thread).
__global__ void k_xmat(VSrc src, bf16* __restrict__ Xh, int n, int Ctot) {
  int C2 = Ctot >> 1;
  int total = n * C2;
  for (int idx = blockIdx.x * blockDim.x + threadIdx.x; idx < total; idx += gridDim.x * blockDim.x) {
    int i = idx / C2;
    int c2 = idx - i * C2;
    float2 v = vloadh2(src, i, c2);
    *(unsigned*)(Xh + (long)i * Ctot + 2 * c2) = pk2(v.x, v.y);
  }
}

// t1[i,:] = sum_t w_t * X[col_t,:] from flat bf16 X; 4 channels per thread.
__global__ void k_prop(const bf16* __restrict__ Xh, float* __restrict__ T, bf16* __restrict__ Th,
                       const int* __restrict__ cnt, const int2* __restrict__ ell,
                       int nbase, int n, int C) {
  int C4 = C >> 2;
  int total = n * C4;
  for (int idx = blockIdx.x * blockDim.x + threadIdx.x; idx < total; idx += gridDim.x * blockDim.x) {
    int i = idx / C4;
    int c = (idx - i * C4) << 2;
    int g = nbase + i;
    int d = cnt[g]; if (d > MAXD) d = MAXD;
    const int2* cols = ell + (long)g * MAXD;
    float a0 = 0.f, a1 = 0.f, a2 = 0.f, a3 = 0.f;
    for (int t = 0; t < d; t += 8) {
      int ci[8]; float wj[8];
#pragma unroll
      for (int j = 0; j < 8; ++j) {
        int tt = t + j;
        int2 e = cols[(tt < d) ? tt : 0];
        ci[j] = e.x;
        wj[j] = (tt < d) ? __int_as_float(e.y) : 0.f;
      }
#pragma unroll
      for (int j = 0; j < 8; ++j) {
        uint2 raw = *(const uint2*)(Xh + (long)ci[j] * C + c);
        float2 v01 = unpk(raw.x);
        float2 v23 = unpk(raw.y);
        a0 += wj[j] * v01.x;
        a1 += wj[j] * v01.y;
        a2 += wj[j] * v23.x;
        a3 += wj[j] * v23.y;
      }
    }
    long o = (long)i * C + c;
    *(float4*)(T + o) = make_float4(a0, a1, a2, a3);
    uint2 pk; pk.x = pk2(a0, a1); pk.y = pk2(a2, a3);
    *(uint2*)(Th + o) = pk;
  }
}

// Fused t2-gather + [X|t1|t2] @ W + b (+relu / +softmax).
// 256 threads = 4 waves. CW waves split K-chunks, 4/CW groups split rows.
template <int ROWS, int CW, int SMAX>
__global__ __launch_bounds__(256) void k_combine(
    VSrc src, const float* __restrict__ T1, const bf16* __restrict__ T1h,
    const float* __restrict__ W, const float* __restrict__ B,
    const int* __restrict__ cnt, const int2* __restrict__ ell,
    int nbase, int n, int Cin, int Cout, int doRelu,
    float* __restrict__ OUT, bf16* __restrict__ OUTh) {
  constexpr int RW = 4 / CW;
  constexpr int RPW = ROWS / RW;

  __shared__ __align__(16) float sx[4][RPW][64];
  __shared__ __align__(16) float st1[4][RPW][64];
  __shared__ __align__(16) float st2[4][RPW][64];

  int tid = threadIdx.x;
  int w = tid >> 6;
  int lane = tid & 63;
  int rg = w / CW;
  int cw = w % CW;

  int colTiles = (Cout + 63) >> 6;
  int ct = blockIdx.x % colTiles;
  int rt = blockIdx.x / colTiles;
  int r0 = rt * ROWS + rg * RPW;
  int o = ct * 64 + lane;
  int oc = (o < Cout) ? o : (Cout - 1);
  int nch = (Cin + 63) >> 6;

  float acc[RPW];
#pragma unroll
  for (int r = 0; r < RPW; ++r) acc[r] = 0.f;

  for (int cg = 0; cg < nch; cg += CW) {
    int c = cg + cw;
    bool act = c < nch;
    int k0 = c * 64;
    int kw = act ? ((Cin - k0 < 64) ? (Cin - k0) : 64) : 0;
    int k = k0 + lane;
    bool kv = act && (lane < kw);

#pragma unroll
    for (int rr = 0; rr < RPW; ++rr) {
      int i = r0 + rr;
      bool iv = i < n;
      float xv = 0.f, tv = 0.f, t2v = 0.f;
      if (kv && iv) {
        xv = vloadf(src, i, k);
        tv = T1[(long)i * Cin + k];
        int g = nbase + i;
        int d = cnt[g]; if (d > MAXD) d = MAXD;
        const int2* cols = ell + (long)g * MAXD;
        float a2 = 0.f;
        for (int t = 0; t < d; t += 8) {
          int ci[8]; float wj[8];
#pragma unroll
          for (int j = 0; j < 8; ++j) {
            int tt = t + j;
            int2 e = cols[(tt < d) ? tt : 0];
            ci[j] = e.x;
            wj[j] = (tt < d) ? __int_as_float(e.y) : 0.f;
          }
#pragma unroll
          for (int j = 0; j < 8; ++j)
            a2 += wj[j] * bf2f(T1h[(long)ci[j] * Cin + k]);
        }
        t2v = 2.f * a2 - xv;
      }
      sx[w][rr][lane] = xv;
      st1[w][rr][lane] = tv;
      st2[w][rr][lane] = t2v;
    }
    __syncthreads();

    int kw4 = kw >> 2;
    long ts = (long)Cin * Cout;
    for (int q = 0; q < kw4; ++q) {
      float w0[4], w1[4], w2[4];
#pragma unroll
      for (int j = 0; j < 4; ++j) {
        long off = (long)(k0 + q * 4 + j) * Cout + oc;
        w0[j] = W[off];
        w1[j] = W[ts + off];
        w2[j] = W[2 * ts + off];
      }
#pragma unroll
      for (int rr = 0; rr < RPW; ++rr) {
        float4 xs = ((const float4*)sx[w][rr])[q];
        float4 t1s = ((const float4*)st1[w][rr])[q];
        float4 t2s = ((const float4*)st2[w][rr])[q];
        acc[rr] += w0[0] * xs.x + w0[1] * xs.y + w0[2] * xs.z + w0[3] * xs.w;
        acc[rr] += w1[0] * t1s.x + w1[1] * t1s.y + w1[2] * t1s.z + w1[3] * t1s.w;
        acc[rr] += w2[0] * t2s.x + w2[1] * t2s.y + w2[2] * t2s.z + w2[3] * t2s.w;
      }
    }
    __syncthreads();
  }

  if constexpr (SMAX) {
    // CW==1, colTiles==1: each wave holds complete logit rows -> softmax in-wave.
    float bb = (o < Cout) ? B[o] : 0.f;
#pragma unroll
    for (int rr = 0; rr < RPW; ++rr) {
      int i = r0 + rr;
      if (i < n) {
        float v = (o < Cout) ? (acc[rr] + bb) : -1e30f;
        float m = v;
        for (int s = 32; s > 0; s >>= 1) m = fmaxf(m, __shfl_xor(m, s));
        float e = (o < Cout) ? __expf(v - m) : 0.f;
        float sum = e;
        for (int s = 32; s > 0; s >>= 1) sum += __shfl_xor(sum, s);
        if (o < Cout) OUT[(long)i * Cout + o] = e / sum;
      }
    }
  } else if constexpr (CW == 1) {
    if (o < Cout) {
      float bb = B[oc];
#pragma unroll
      for (int rr = 0; rr < RPW; ++rr) {
        int i = r0 + rr;
        if (i < n) {
          float v = acc[rr] + bb;
          if (doRelu) v = fmaxf(v, 0.f);
          long off = (long)i * Cout + o;
          OUT[off] = v;
          OUTh[off] = __float2bfloat16(v);
        }
      }
    }
  } else {
#pragma unroll
    for (int rr = 0; rr < RPW; ++rr) sx[w][rr][lane] = acc[rr];
    __syncthreads();
    if (cw == 0 && o < Cout) {
      float bb = B[oc];
#pragma unroll
      for (int rr = 0; rr < RPW; ++rr) {
        int i = r0 + rr;
        if (i < n) {
          float v = bb;
#pragma unroll
          for (int j = 0; j < CW; ++j) v += sx[rg * CW + j][rr][lane];
          if (doRelu) v = fmaxf(v, 0.f);
          long off = (long)i * Cout + o;
          OUT[off] = v;
          OUTh[off] = __float2bfloat16(v);
        }
      }
    }
  }
}

extern "C" void kernel_launch(void* const* d_in, const int* in_sizes, int n_in,
                              void* d_out, int out_size, void* d_ws, size_t ws_size,
                              hipStream_t stream) {
  static const int NV[6] = {42, 162, 642, 2562, 10242, 40962};
  static const int NE[6] = {240, 960, 3840, 15360, 61440, 245760};
  const int NT = 54612;
  const int ET = 327600;

  EdgeParams ep;
  {
    int nb = 0, eb = 0;
    for (int l = 0; l < 6; ++l) {
      ep.e[l] = (const int*)d_in[1 + l];
      ep.E[l] = NE[l];
      ep.ebase[l] = eb;
      ep.nbase[l] = nb;
      eb += NE[l];
      nb += NV[l];
    }
  }
  const float* x0f = (const float*)d_in[0];
  const int* up[5];
  for (int i = 0; i < 5; ++i) up[i] = (const int*)d_in[7 + i];  // up2..up6
  const float *W[11], *Bb[11];
  for (int i = 0; i < 11; ++i) {
    W[i] = (const float*)d_in[12 + 2 * i];
    Bb[i] = (const float*)d_in[13 + 2 * i];
  }

  // ---- workspace carve (16B-aligned blocks) ----
  char* p = (char*)d_ws;
  auto alloc_b = [&](size_t bytes) { void* r = (void*)p; p += (bytes + 15) & ~size_t(15); return r; };
  auto alloc_i = [&](size_t ne) { return (int*)alloc_b(ne * 4); };
  auto alloc_f = [&](size_t ne) { return (float*)alloc_b(ne * 4); };
  auto alloc_h = [&](size_t ne) { return (bf16*)alloc_b(ne * 2); };
  int* cnt = alloc_i(NT);
  int2* ell = (int2*)alloc_b((size_t)NT * MAXD * 8);
  float* t1f = alloc_f((size_t)40962 * 36);
  bf16* t1h = alloc_h((size_t)40962 * 36);
  bf16* x0h = alloc_h((size_t)40962 * 4);
  bf16* xh = alloc_h((size_t)40962 * 36);  // decoder materialized upcat source
  float *af[11]; bf16 *ah[11];
  const int an[11] = {40962, 10242, 2562, 642, 162, 42, 162, 642, 2562, 10242, 0};
  const int ac[11] = {32, 64, 128, 256, 512, 512, 256, 128, 64, 32, 0};
  for (int i = 0; i < 10; ++i) {
    af[i] = alloc_f((size_t)an[i] * ac[i]);
    ah[i] = alloc_h((size_t)an[i] * ac[i]);
  }

  hipMemsetAsync(cnt, 0, (size_t)NT * 4, stream);
  k_fill<<<(ET + 255) / 256, 256, 0, stream>>>(ep, cnt, ell, ET);
  k_wfill<<<(NT * MAXD + 255) / 256, 256, 0, stream>>>(ep, cnt, ell, NT);
  k_cvt<<<(40962 * 4 + 255) / 256, 256, 0, stream>>>(x0f, x0h, 40962 * 4);

  auto cheb = [&](const bf16* Xh, VSrc src, float* OUT, bf16* OUTh, int lvl, int n, int Cin,
                  int Cout, const float* Wp, const float* Bp, int relu, int rows, int cwv, int smax) {
    int nb = ep.nbase[lvl];
    int total4 = n * (Cin >> 2);
    k_prop<<<(total4 + 255) / 256, 256, 0, stream>>>(Xh, t1f, t1h, cnt, ell, nb, n, Cin);
    int colTiles = (Cout + 63) / 64;
    int rowTiles = (n + rows - 1) / rows;
    dim3 grid(colTiles * rowTiles);
    if (smax)
      k_combine<16, 1, 1><<<grid, 256, 0, stream>>>(src, t1f, t1h, Wp, Bp, cnt, ell, nb, n, Cin, Cout, relu, OUT, OUTh);
    else if (rows == 16)
      k_combine<16, 1, 0><<<grid, 256, 0, stream>>>(src, t1f, t1h, Wp, Bp, cnt, ell, nb, n, Cin, Cout, relu, OUT, OUTh);
    else if (rows == 8 && cwv == 1)
      k_combine<8, 1, 0><<<grid, 256, 0, stream>>>(src, t1f, t1h, Wp, Bp, cnt, ell, nb, n, Cin, Cout, relu, OUT, OUTh);
    else if (rows == 8 && cwv == 2)
      k_combine<8, 2, 0><<<grid, 256, 0, stream>>>(src, t1f, t1h, Wp, Bp, cnt, ell, nb, n, Cin, Cout, relu, OUT, OUTh);
    else
      k_combine<4, 4, 0><<<grid, 256, 0, stream>>>(src, t1f, t1h, Wp, Bp, cnt, ell, nb, n, Cin, Cout, relu, OUT, OUTh);
  };

  auto plain = [](const float* hf, const bf16* hh, int Ch) {
    VSrc s{hf, hh, nullptr, nullptr, nullptr, 0, Ch, 0}; return s;
  };
  auto upsrc = [](const float* hf, const bf16* hh, const float* skf, const bf16* skh,
                  const int* u, int nprev, int Ch, int Cs) {
    VSrc s{hf, hh, skf, skh, u, nprev, Ch, Cs}; return s;
  };

  // encoder (prop reads flat bf16 shadows directly)
  cheb(x0h, plain(x0f, x0h, 4), af[0], ah[0], 5, 40962, 4, 32, W[0], Bb[0], 1, 16, 1, 0);
  cheb(ah[0], plain(af[0], ah[0], 32), af[1], ah[1], 4, 10242, 32, 64, W[1], Bb[1], 1, 8, 1, 0);
  cheb(ah[1], plain(af[1], ah[1], 64), af[2], ah[2], 3, 2562, 64, 128, W[2], Bb[2], 1, 8, 1, 0);
  cheb(ah[2], plain(af[2], ah[2], 128), af[3], ah[3], 2, 642, 128, 256, W[3], Bb[3], 1, 8, 2, 0);
  cheb(ah[3], plain(af[3], ah[3], 256), af[4], ah[4], 1, 162, 256, 512, W[4], Bb[4], 1, 4, 4, 0);
  cheb(ah[4], plain(af[4], ah[4], 512), af[5], ah[5], 0, 42, 512, 512, W[5], Bb[5], 1, 4, 4, 0);

  // decoder: materialize upcat source to flat bf16, then cheb
  auto dec = [&](const float* hf, const bf16* hh, const float* skf, const bf16* skh,
                 const int* u, int nprev, int Ch, int Cs, float* OUT, bf16* OUTh, int lvl,
                 int n, int Cout, const float* Wp, const float* Bp, int relu, int rows,
                 int cwv, int smax) {
    int Cin = Ch + Cs;
    VSrc src = upsrc(hf, hh, skf, skh, u, nprev, Ch, Cs);
    int total2 = n * (Cin >> 1);
    k_xmat<<<(total2 + 255) / 256, 256, 0, stream>>>(src, xh, n, Cin);
    cheb(xh, src, OUT, OUTh, lvl, n, Cin, Cout, Wp, Bp, relu, rows, cwv, smax);
  };

  dec(af[5], ah[5], af[3], ah[3], up[0], 42, 512, 256, af[6], ah[6], 1, 162, 256, W[6], Bb[6], 1, 4, 4, 0);
  dec(af[6], ah[6], af[2], ah[2], up[1], 162, 256, 128, af[7], ah[7], 2, 642, 128, W[7], Bb[7], 1, 4, 4, 0);
  dec(af[7], ah[7], af[1], ah[1], up[2], 642, 128, 64, af[8], ah[8], 3, 2562, 64, W[8], Bb[8], 1, 8, 2, 0);
  dec(af[8], ah[8], af[0], ah[0], up[3], 2562, 64, 32, af[9], ah[9], 4, 10242, 32, W[9], Bb[9], 1, 8, 2, 0);
  // final layer: softmax fused, writes d_out directly
  dec(af[9], ah[9], x0f, x0h, up[4], 10242, 32, 4, (float*)d_out, nullptr, 5, 40962, 37, W[10], Bb[10], 0, 16, 1, 1);
}